// Round 8
// baseline (122.323 us; speedup 1.0000x reference)
//
#include <hip/hip_runtime.h>
#include <stdint.h>

typedef unsigned long long u64;
typedef unsigned int u32;

#define NC 80
#define CONF_T 0.25f
#define IOU_THR 0.45f
#define MAX_DET 300
#define KBIG 1024
#define A_ANCH 8400
#define NROWS 84
#define MAX_WH 7680.0f
#define HBINS 65536

// ---------------- Kernel 1: conf/argmax -> keys + offset boxes + 64K-bin score histogram ----------------
// key = (score_bits << 32) | ((16383 - anchor) << 7) | cls
__global__ __launch_bounds__(256) void yolo_conf_kernel(const float* __restrict__ preds,
                                                        u64* __restrict__ keys,
                                                        float4* __restrict__ obox,
                                                        u32* __restrict__ hist) {
    int b = blockIdx.x / 9;
    int g = (blockIdx.x % 9) * 256 + threadIdx.x;   // group of 4 anchors
    if (g >= A_ANCH / 4) return;
    int a0 = g * 4;
    const float* base = preds + ((size_t)b * NROWS + 4) * A_ANCH + a0;
    float4 best = *(const float4*)base;
    int bcx = 0, bcy = 0, bcz = 0, bcw = 0;
#pragma unroll 4
    for (int c = 1; c < NC; ++c) {
        float4 v = *(const float4*)(base + (size_t)c * A_ANCH);
        if (v.x > best.x) { best.x = v.x; bcx = c; }   // strict > = first-max argmax
        if (v.y > best.y) { best.y = v.y; bcy = c; }
        if (v.z > best.z) { best.z = v.z; bcz = c; }
        if (v.w > best.w) { best.w = v.w; bcw = c; }
    }
    float sc[4] = {(best.x > CONF_T) ? best.x : 0.0f, (best.y > CONF_T) ? best.y : 0.0f,
                   (best.z > CONF_T) ? best.z : 0.0f, (best.w > CONF_T) ? best.w : 0.0f};
    int cl[4] = {bcx, bcy, bcz, bcw};
    u64* ko = keys + (size_t)b * A_ANCH + a0;
    ulonglong2 k01, k23;
    k01.x = ((u64)__float_as_uint(sc[0]) << 32) | ((u64)(16383 - a0) << 7) | (u64)cl[0];
    k01.y = ((u64)__float_as_uint(sc[1]) << 32) | ((u64)(16383 - (a0 + 1)) << 7) | (u64)cl[1];
    k23.x = ((u64)__float_as_uint(sc[2]) << 32) | ((u64)(16383 - (a0 + 2)) << 7) | (u64)cl[2];
    k23.y = ((u64)__float_as_uint(sc[3]) << 32) | ((u64)(16383 - (a0 + 3)) << 7) | (u64)cl[3];
    *(ulonglong2*)ko = k01;
    *(ulonglong2*)(ko + 2) = k23;

    // offset boxes (bit-exact chain: x1 = x - w*0.5 ; bx1 = x1 + cls*7680)
    const float* pb = preds + (size_t)b * NROWS * A_ANCH + a0;
    float4 xv = *(const float4*)(pb);
    float4 yv = *(const float4*)(pb + A_ANCH);
    float4 wv = *(const float4*)(pb + 2 * A_ANCH);
    float4 hv = *(const float4*)(pb + 3 * A_ANCH);
    float xs[4] = {xv.x, xv.y, xv.z, xv.w};
    float ys[4] = {yv.x, yv.y, yv.z, yv.w};
    float ws[4] = {wv.x, wv.y, wv.z, wv.w};
    float hs[4] = {hv.x, hv.y, hv.z, hv.w};
    u32* hb = hist + (size_t)b * HBINS;
#pragma unroll
    for (int q = 0; q < 4; ++q) {
        float hw = __fmul_rn(ws[q], 0.5f), hh = __fmul_rn(hs[q], 0.5f);
        float x1 = __fsub_rn(xs[q], hw), x2 = __fadd_rn(xs[q], hw);
        float y1 = __fsub_rn(ys[q], hh), y2 = __fadd_rn(ys[q], hh);
        float off = __fmul_rn((float)cl[q], MAX_WH);
        float4 ob;
        ob.x = __fadd_rn(x1, off); ob.y = __fadd_rn(y1, off);
        ob.z = __fadd_rn(x2, off); ob.w = __fadd_rn(y2, off);
        obox[(size_t)b * A_ANCH + a0 + q] = ob;
        atomicAdd(&hb[__float_as_uint(sc[q]) >> 16], 1u);
    }
}

__device__ __forceinline__ float iou_f(float ix1, float iy1, float ix2, float iy2, float iar,
                                       float jx1, float jy1, float jx2, float jy2, float jar) {
    float lx = fmaxf(ix1, jx1), ly = fmaxf(iy1, jy1);
    float rx = fminf(ix2, jx2), ry = fminf(iy2, jy2);
    float ww = fmaxf(__fsub_rn(rx, lx), 0.0f);
    float hh = fmaxf(__fsub_rn(ry, ly), 0.0f);
    float inter = __fmul_rn(ww, hh);
    float den = __fadd_rn(__fsub_rn(__fadd_rn(iar, jar), inter), 1e-7f);
    return __fdiv_rn(inter, den);
}

__device__ __forceinline__ void hadd(u32* h, u32 bin, bool m, int lane) {
    u64 act = __ballot(m);
    if (act == 0) return;
    int fl = __ffsll((unsigned long long)act) - 1;
    u32 fb = __shfl(bin, fl);
    u64 same = __ballot(m && (bin == fb));
    if (lane == fl) atomicAdd(&h[fb], (u32)__popcll(same));
    if (m && (bin != fb)) atomicAdd(&h[bin], 1u);
}

__device__ __forceinline__ u64 bstep(u64 v, u32 idx, u32 size, u32 stride) {
    u64 v2 = __shfl_xor((unsigned long long)v, (int)stride, 64);
    bool keep_big = (((idx & stride) == 0) == ((idx & size) == 0));
    return ((v > v2) == keep_big) ? v : v2;
}

__device__ __forceinline__ void radix_scan(u32* hist, int nb, int shift, u32* s_scal,
                                           u32* wsum, int tid, int lane, int wid) {
    int per = nb >> 10; if (per == 0) per = 1;
    int na = nb / per;
    u32 rem = s_scal[1];
    u32 Pk = s_scal[0];
    int hi = nb - 1 - per * tid;
    u32 s = 0;
    if (tid < na)
        for (int q = 0; q < per; ++q) s += hist[hi - q];
    u32 pre = s;
#pragma unroll
    for (int off = 1; off < 64; off <<= 1) {
        u32 o = __shfl_up(pre, off);
        if (lane >= off) pre += o;
    }
    if (lane == 63) wsum[wid] = pre;
    __syncthreads();
    u32 base = 0;
    for (int w = 0; w < wid; ++w) base += wsum[w];
    u32 run = base + pre - s;
    if (tid < na) {
        for (int q = 0; q < per; ++q) {
            int d = hi - q;
            u32 g = hist[d];
            if (run < rem && rem <= run + g) {
                s_scal[0] = Pk | ((u32)d << shift);
                s_scal[1] = rem - run;
            }
            run += g;
        }
    }
    __syncthreads();
}

union U2 {
    u32 hist[4096];
    struct { u32 eqw[264]; u32 wpre[264]; } tie;
};

// ---------------- Kernel 2: bin-select (fast) / exact radix (fallback) + sort + NMS + emit ----------------
__global__ __launch_bounds__(1024) void yolo_nms_kernel(const float* __restrict__ preds,
                                                        const u64* __restrict__ keys,
                                                        const float4* __restrict__ obox,
                                                        const u32* __restrict__ hist,
                                                        float* __restrict__ out) {
    const int b = blockIdx.x;
    const int tid = threadIdx.x;
    const int lane = tid & 63;
    const int wid = tid >> 6;   // 0..15

    __shared__ U2 u2;
    __shared__ u64 skey[KBIG];
    __shared__ float BX1[KBIG], BY1[KBIG], BX2[KBIG], BY2[KBIG], BAR[KBIG];
    __shared__ int keptlist[364];
    __shared__ float kx1[364], ky1[364], kx2[364], ky2[364], kar[364];
    __shared__ u32 kcls[364];
    __shared__ u64 rows[64];
    __shared__ u32 wsum[16];
    __shared__ u32 s_scal[4];
    __shared__ u32 s_csupp[2];
    __shared__ u32 s_nkept;
    __shared__ u32 s_valid;

    const u64* kb = keys + (size_t)b * A_ANCH;

    // score bits in registers
    u32 vals[9];
#pragma unroll
    for (int it = 0; it < 9; ++it) {
        int a = tid + it * 1024;
        vals[it] = (a < A_ANCH) ? (u32)(kb[a] >> 32) : 0u;
    }
    if (tid == 0) s_valid = 0;
    __syncthreads();
    {
        u32 c = 0;
#pragma unroll
        for (int it = 0; it < 9; ++it) c += (vals[it] != 0u) ? 1u : 0u;
#pragma unroll
        for (int off = 32; off >= 1; off >>= 1) c += __shfl_xor(c, off);
        if (lane == 0) atomicAdd(&s_valid, c);
    }

    // ---- hierarchical scan of the prebuilt 64K hist: bin of the 512th-largest score ----
    const u32* hb = hist + (size_t)b * HBINS;
    {
        const uint4* hb4 = (const uint4*)hb;
        u32 tsum = 0;
#pragma unroll
        for (int q = 0; q < 16; ++q) {
            uint4 v = hb4[tid * 16 + q];
            tsum += v.x + v.y + v.z + v.w;
        }
        u32 pre = tsum;   // inclusive suffix within wave (desc bins = desc lanes)
#pragma unroll
        for (int off = 1; off < 64; off <<= 1) {
            u32 o = __shfl_down(pre, off);
            if (lane + off < 64) pre += o;
        }
        if (lane == 0) wsum[wid] = pre;
        __syncthreads();
        u32 above = pre - tsum;
        for (int w = wid + 1; w < 16; ++w) above += wsum[w];
        if (above < 512u && 512u <= above + tsum) { s_scal[0] = (u32)tid; s_scal[1] = above; }
        __syncthreads();
        if (wid == 0) {
            u32 t = s_scal[0], baseAbove = s_scal[1];
            u32 g = hb[t * 64 + 63 - lane];   // lane 0 = highest bin of the range
            u32 p = g;
#pragma unroll
            for (int off = 1; off < 64; off <<= 1) {
                u32 o = __shfl_up(p, off);
                if (lane >= off) p += o;
            }
            u32 run = baseAbove + p - g;      // count in bins above this lane's bin
            if (run < 512u && 512u <= run + g) {
                s_scal[0] = t * 64 + 63 - lane;   // Pbin
                s_scal[1] = run;                   // count > Pbin
                s_scal[2] = run + g;               // C = count >= Pbin
            }
        }
        __syncthreads();
    }
    const u32 Pbin = s_scal[0];
    const u32 Cfast = s_scal[2];
    const u32 validN = s_valid;

    for (int pass = 0; pass < 2; ++pass) {
        u32 Ccand;
        if (pass == 0) {
            if (Cfast > (u32)KBIG) continue;   // degenerate ties -> exact path
            Ccand = Cfast;
            skey[tid] = 0;
            if (tid == 0) { s_scal[3] = 0; s_nkept = 0; s_csupp[0] = 0; s_csupp[1] = 0; }
            __syncthreads();
            // compact all candidates with bin >= Pbin (order random; sort makes prefix exact)
#pragma unroll
            for (int it = 0; it < 9; ++it) {
                int a = tid + it * 1024;
                bool take = (a < A_ANCH) && ((vals[it] >> 16) >= Pbin) && (vals[it] != 0u);
                u64 m = __ballot(take);
                if (m) {
                    int fl = __ffsll((unsigned long long)m) - 1;
                    u32 basep = 0;
                    if (lane == fl) basep = atomicAdd(&s_scal[3], (u32)__popcll(m));
                    basep = __shfl(basep, fl);
                    if (take) {
                        u32 pos = basep + (u32)__popcll(m & ((1ull << lane) - 1ull));
                        if (pos < (u32)KBIG) skey[pos] = kb[a];
                    }
                }
            }
            __syncthreads();
        } else {
            // ---- exact top-1024 radix select (fallback; retained from r7) ----
            for (int i = tid; i < 4096; i += 1024) u2.hist[i] = 0;
            if (tid == 0) {
                s_scal[0] = 0; s_scal[1] = (u32)KBIG; s_scal[2] = 0;
                s_nkept = 0; s_csupp[0] = 0; s_csupp[1] = 0;
            }
            __syncthreads();
#pragma unroll
            for (int it = 0; it < 9; ++it) {
                int a = tid + it * 1024;
                hadd(u2.hist, vals[it] >> 20, a < A_ANCH, lane);
            }
            __syncthreads();
            radix_scan(u2.hist, 4096, 20, s_scal, wsum, tid, lane, wid);
            for (int i = tid; i < 4096; i += 1024) u2.hist[i] = 0;
            __syncthreads();
            u32 Pk = s_scal[0];
#pragma unroll
            for (int it = 0; it < 9; ++it) {
                int a = tid + it * 1024;
                u32 v = vals[it];
                bool m = (a < A_ANCH) && ((v & 0xFFF00000u) == Pk);
                hadd(u2.hist, (v >> 8) & 4095u, m, lane);
            }
            __syncthreads();
            radix_scan(u2.hist, 4096, 8, s_scal, wsum, tid, lane, wid);
            for (int i = tid; i < 256; i += 1024) u2.hist[i] = 0;
            __syncthreads();
            Pk = s_scal[0];
#pragma unroll
            for (int it = 0; it < 9; ++it) {
                int a = tid + it * 1024;
                u32 v = vals[it];
                bool m = (a < A_ANCH) && ((v & 0xFFFFFF00u) == Pk);
                hadd(u2.hist, v & 255u, m, lane);
            }
            __syncthreads();
            radix_scan(u2.hist, 256, 0, s_scal, wsum, tid, lane, wid);
            const u32 P = s_scal[0];
            const u32 tEq = s_scal[1];
            if (tid < 264) u2.tie.eqw[tid] = 0;
            __syncthreads();
#pragma unroll
            for (int it = 0; it < 9; ++it) {
                int a = tid + it * 1024;
                if (a < A_ANCH && vals[it] == P) atomicOr(&u2.tie.eqw[a >> 5], 1u << (a & 31));
            }
            __syncthreads();
            if (wid == 0) {
                u32 cw[5], loc = 0;
#pragma unroll
                for (int q = 0; q < 5; ++q) {
                    int w2 = lane * 5 + q;
                    u32 e = (w2 < 264) ? u2.tie.eqw[w2] : 0u;
                    cw[q] = (u32)__popc(e); loc += cw[q];
                }
                u32 pre = loc;
#pragma unroll
                for (int off = 1; off < 64; off <<= 1) {
                    u32 o = __shfl_up(pre, off);
                    if (lane >= off) pre += o;
                }
                u32 run = pre - loc;
#pragma unroll
                for (int q = 0; q < 5; ++q) {
                    int w2 = lane * 5 + q;
                    if (w2 < 264) u2.tie.wpre[w2] = run;
                    run += cw[q];
                }
            }
            __syncthreads();
#pragma unroll
            for (int it = 0; it < 9; ++it) {
                int a = tid + it * 1024;
                bool take = false;
                if (a < A_ANCH) {
                    u32 v = vals[it];
                    take = v > P;
                    if (!take && v == P) {
                        u32 r = u2.tie.wpre[a >> 5] +
                                (u32)__popc(u2.tie.eqw[a >> 5] & ((1u << (a & 31)) - 1u));
                        take = (r < tEq);
                    }
                }
                u64 m = __ballot(take);
                if (m) {
                    int fl = __ffsll((unsigned long long)m) - 1;
                    u32 basep = 0;
                    if (lane == fl) basep = atomicAdd(&s_scal[2], (u32)__popcll(m));
                    basep = __shfl(basep, fl);
                    if (take) {
                        u32 pos = basep + (u32)__popcll(m & ((1ull << lane) - 1ull));
                        if (pos < (u32)KBIG) skey[pos] = kb[a];
                    }
                }
            }
            __syncthreads();
            Ccand = KBIG;
        }

        // ---- hybrid bitonic sort of 1024, descending (unique keys -> deterministic) ----
        {
            u64 v = skey[tid];
#pragma unroll
            for (u32 size = 2; size <= 64; size <<= 1)
#pragma unroll
                for (u32 stride = size >> 1; stride >= 1; stride >>= 1)
                    v = bstep(v, (u32)tid, size, stride);
            for (u32 size = 128; size <= 1024; size <<= 1) {
                for (u32 stride = size >> 1; stride >= 64; stride >>= 1) {
                    skey[tid] = v;
                    __syncthreads();
                    u64 v2 = skey[tid ^ stride];
                    bool keep_big = ((((u32)tid & stride) == 0) == (((u32)tid & size) == 0));
                    v = ((v > v2) == keep_big) ? v : v2;
                    __syncthreads();
                }
#pragma unroll
                for (u32 stride = 32; stride >= 1; stride >>= 1)
                    v = bstep(v, (u32)tid, size, stride);
            }
            skey[tid] = v;
            __syncthreads();
        }

        // ---- boxes: one float4 gather from precomputed obox ----
        {
            u64 key = skey[tid];
            int idx = 16383 - (int)((key >> 7) & 16383u);
            if (idx >= A_ANCH || idx < 0) idx = 0;   // zero-pad keys decode out of range; scores 0 -> inert
            float4 ob = obox[(size_t)b * A_ANCH + idx];
            BX1[tid] = ob.x; BY1[tid] = ob.y; BX2[tid] = ob.z; BY2[tid] = ob.w;
            BAR[tid] = __fmul_rn(__fsub_rn(ob.z, ob.x), __fsub_rn(ob.w, ob.y));
        }
        __syncthreads();

        // ---- greedy NMS over chunks of 64 ----
        const int nchunks = (int)((Ccand + 63u) >> 6);
        for (int c = 0; c < nchunks; ++c) {
            int j = c * 64 + lane;
            u64 keyj = skey[j];
            float scj = __uint_as_float((u32)(keyj >> 32));
            u32 clsj = (u32)(keyj & 127u);
            float jx1 = BX1[j], jy1 = BY1[j], jx2 = BX2[j], jy2 = BY2[j], jar = BAR[j];

            u32 nk = s_nkept;
            bool suppbit = false;
            for (u32 k = wid; k < nk; k += 16) {
                bool cm = (kcls[k] == clsj);
                if (__ballot(cm)) {
                    float iou = iou_f(kx1[k], ky1[k], kx2[k], ky2[k], kar[k],
                                      jx1, jy1, jx2, jy2, jar);
                    suppbit |= (cm && (iou > IOU_THR));
                }
            }
            u64 bm = __ballot(suppbit);
            if (bm && lane == 0) {
                atomicOr(&s_csupp[0], (u32)bm);
                atomicOr(&s_csupp[1], (u32)(bm >> 32));
            }
#pragma unroll
            for (int p2 = 0; p2 < 4; ++p2) {
                int i = p2 * 16 + wid;
                int ci = c * 64 + i;
                u32 clsi = (u32)(skey[ci] & 127u);
                u64 m = 0;
                if (__ballot(clsi == clsj)) {
                    float iou = iou_f(BX1[ci], BY1[ci], BX2[ci], BY2[ci], BAR[ci],
                                      jx1, jy1, jx2, jy2, jar);
                    m = __ballot((lane > i) && (iou > IOU_THR));
                }
                if (lane == 0) rows[i] = m;
            }
            __syncthreads();
            if (wid == 0) {
                u64 row = rows[lane];
                u32 rlo = (u32)row, rhi = (u32)(row >> 32);
                u64 csupp = (((u64)s_csupp[1]) << 32) | (u64)s_csupp[0];
                u64 validm = __ballot(scj > CONF_T) & ~csupp;
                u64 supp = 0, keep = 0;
#pragma unroll
                for (int i = 0; i < 64; ++i) {
                    u64 ri = (((u64)(u32)__builtin_amdgcn_readlane((int)rhi, i)) << 32) |
                             (u64)(u32)__builtin_amdgcn_readlane((int)rlo, i);
                    bool ki = (((validm & ~supp) >> i) & 1ull) != 0;
                    if (ki) { keep |= (1ull << i); supp |= ri; }
                }
                u32 basek = s_nkept;
                if ((keep >> lane) & 1ull) {
                    u32 slot = basek + (u32)__popcll(keep & ((1ull << lane) - 1ull));
                    keptlist[slot] = j;
                    kx1[slot] = jx1; ky1[slot] = jy1;
                    kx2[slot] = jx2; ky2[slot] = jy2;
                    kar[slot] = jar; kcls[slot] = clsj;
                }
                if (lane == 0) {
                    s_nkept = basek + (u32)__popcll(keep);
                    s_csupp[0] = 0; s_csupp[1] = 0;
                }
            }
            __syncthreads();
            if (s_nkept >= MAX_DET) break;
        }

        u32 nk = s_nkept;
        bool finished = (nk >= MAX_DET) || (Ccand >= validN) || (pass == 1);
        if (!finished) continue;   // exact fallback (not taken on bench data)

        // ---- emit (plain boxes recomputed from preds: bit-exact) ----
        if (tid < MAX_DET) {
            float row[6];
            int t = (tid < (int)(nk < MAX_DET ? nk : MAX_DET)) ? keptlist[tid] : -1;
            if (t >= 0) {
                u64 key = skey[t];
                float score = __uint_as_float((u32)(key >> 32));
                int cls = (int)(key & 127u);
                int idx = 16383 - (int)((key >> 7) & 16383u);
                const float* pb = preds + (size_t)b * NROWS * A_ANCH + idx;
                float x = pb[0], y = pb[A_ANCH], w = pb[2 * A_ANCH], h = pb[3 * A_ANCH];
                float hw = __fmul_rn(w, 0.5f), hh = __fmul_rn(h, 0.5f);
                row[0] = __fsub_rn(x, hw);
                row[1] = __fsub_rn(y, hh);
                row[2] = __fadd_rn(x, hw);
                row[3] = __fadd_rn(y, hh);
                row[4] = score;
                row[5] = (float)cls;
            } else {
                row[0] = row[1] = row[2] = row[3] = row[4] = row[5] = (float)NC;
            }
            float* o = out + ((size_t)b * MAX_DET + tid) * 6;
#pragma unroll
            for (int q = 0; q < 6; ++q) o[q] = row[q];
        }
        break;
    }
}

extern "C" void kernel_launch(void* const* d_in, const int* in_sizes, int n_in,
                              void* d_out, int out_size, void* d_ws, size_t ws_size,
                              hipStream_t stream) {
    const float* preds = (const float*)d_in[0];
    float* out = (float*)d_out;
    int B = in_sizes[0] / (NROWS * A_ANCH);
    u64* keys = (u64*)d_ws;                                   // B*8400 u64   (2.15 MB @B=32)
    float4* obox = (float4*)(keys + (size_t)B * A_ANCH);      // B*8400 f4    (4.30 MB)
    u32* hist = (u32*)(obox + (size_t)B * A_ANCH);            // B*65536 u32  (8.39 MB)
    (void)hipMemsetAsync(hist, 0, (size_t)B * HBINS * sizeof(u32), stream);
    yolo_conf_kernel<<<dim3(B * 9), dim3(256), 0, stream>>>(preds, keys, obox, hist);
    yolo_nms_kernel<<<dim3(B), dim3(1024), 0, stream>>>(preds, keys, obox, hist, out);
}

// Round 9
// 78.487 us; speedup vs baseline: 1.5585x; 1.5585x over previous
//
#include <hip/hip_runtime.h>
#include <stdint.h>

typedef unsigned long long u64;
typedef unsigned int u32;

#define NC 80
#define CONF_T 0.25f
#define IOU_THR 0.45f
#define MAX_DET 300
#define KBIG 1024
#define A_ANCH 8400
#define NROWS 84
#define MAX_WH 7680.0f
#define HBINS 256
#define BIN_BASE 0x3e80u

// adaptive wave histogram add: 1 atomic for the dominant bin, per-lane for stragglers
__device__ __forceinline__ void hadd(u32* h, u32 bin, bool m, int lane) {
    u64 act = __ballot(m);
    if (act == 0) return;
    int fl = __ffsll((unsigned long long)act) - 1;
    u32 fb = __shfl(bin, fl);
    u64 same = __ballot(m && (bin == fb));
    if (lane == fl) atomicAdd(&h[fb], (u32)__popcll(same));
    if (m && (bin != fb)) atomicAdd(&h[bin], 1u);
}

// ---------------- Kernel 1: conf/argmax -> keys + offset boxes + 256-bin LDS hist ----------------
// key = (score_bits << 32) | ((16383 - anchor) << 7) | cls
__global__ __launch_bounds__(256) void yolo_conf_kernel(const float* __restrict__ preds,
                                                        u64* __restrict__ keys,
                                                        float4* __restrict__ obox,
                                                        u32* __restrict__ hist) {
    __shared__ u32 lh[HBINS];
    const int lane = threadIdx.x & 63;
    int b = blockIdx.x / 9;
    int g = (blockIdx.x % 9) * 256 + threadIdx.x;   // group of 4 anchors
    lh[threadIdx.x] = 0;
    __syncthreads();

    if (g < A_ANCH / 4) {
        int a0 = g * 4;
        const float* base = preds + ((size_t)b * NROWS + 4) * A_ANCH + a0;
        float4 best = *(const float4*)base;
        int bcx = 0, bcy = 0, bcz = 0, bcw = 0;
#pragma unroll 4
        for (int c = 1; c < NC; ++c) {
            float4 v = *(const float4*)(base + (size_t)c * A_ANCH);
            if (v.x > best.x) { best.x = v.x; bcx = c; }   // strict > = first-max argmax
            if (v.y > best.y) { best.y = v.y; bcy = c; }
            if (v.z > best.z) { best.z = v.z; bcz = c; }
            if (v.w > best.w) { best.w = v.w; bcw = c; }
        }
        float sc[4] = {(best.x > CONF_T) ? best.x : 0.0f, (best.y > CONF_T) ? best.y : 0.0f,
                       (best.z > CONF_T) ? best.z : 0.0f, (best.w > CONF_T) ? best.w : 0.0f};
        int cl[4] = {bcx, bcy, bcz, bcw};
        u64* ko = keys + (size_t)b * A_ANCH + a0;
        ulonglong2 k01, k23;
        k01.x = ((u64)__float_as_uint(sc[0]) << 32) | ((u64)(16383 - a0) << 7) | (u64)cl[0];
        k01.y = ((u64)__float_as_uint(sc[1]) << 32) | ((u64)(16383 - (a0 + 1)) << 7) | (u64)cl[1];
        k23.x = ((u64)__float_as_uint(sc[2]) << 32) | ((u64)(16383 - (a0 + 2)) << 7) | (u64)cl[2];
        k23.y = ((u64)__float_as_uint(sc[3]) << 32) | ((u64)(16383 - (a0 + 3)) << 7) | (u64)cl[3];
        *(ulonglong2*)ko = k01;
        *(ulonglong2*)(ko + 2) = k23;

        // offset boxes (bit-exact chain: x1 = x - w*0.5 ; bx1 = x1 + cls*7680)
        const float* pb = preds + (size_t)b * NROWS * A_ANCH + a0;
        float4 xv = *(const float4*)(pb);
        float4 yv = *(const float4*)(pb + A_ANCH);
        float4 wv = *(const float4*)(pb + 2 * A_ANCH);
        float4 hv = *(const float4*)(pb + 3 * A_ANCH);
        float xs[4] = {xv.x, xv.y, xv.z, xv.w};
        float ys[4] = {yv.x, yv.y, yv.z, yv.w};
        float ws[4] = {wv.x, wv.y, wv.z, wv.w};
        float hs[4] = {hv.x, hv.y, hv.z, hv.w};
#pragma unroll
        for (int q = 0; q < 4; ++q) {
            float hw = __fmul_rn(ws[q], 0.5f), hh = __fmul_rn(hs[q], 0.5f);
            float x1 = __fsub_rn(xs[q], hw), x2 = __fadd_rn(xs[q], hw);
            float y1 = __fsub_rn(ys[q], hh), y2 = __fadd_rn(ys[q], hh);
            float off = __fmul_rn((float)cl[q], MAX_WH);
            float4 ob;
            ob.x = __fadd_rn(x1, off); ob.y = __fadd_rn(y1, off);
            ob.z = __fadd_rn(x2, off); ob.w = __fadd_rn(y2, off);
            obox[(size_t)b * A_ANCH + a0 + q] = ob;
            u32 sb = __float_as_uint(sc[q]);
            u32 bin = (sb >> 16) - BIN_BASE;
            if (bin > 255u) bin = 255u;      // defensive clamp (score==1.0)
            hadd(lh, bin, sb != 0u, lane);   // LDS hist: valid scores only
        }
    }
    __syncthreads();
    u32 c = lh[threadIdx.x];
    if (c) atomicAdd(&hist[(size_t)b * HBINS + threadIdx.x], c);
}

__device__ __forceinline__ float iou_f(float ix1, float iy1, float ix2, float iy2, float iar,
                                       float jx1, float jy1, float jx2, float jy2, float jar) {
    float lx = fmaxf(ix1, jx1), ly = fmaxf(iy1, jy1);
    float rx = fminf(ix2, jx2), ry = fminf(iy2, jy2);
    float ww = fmaxf(__fsub_rn(rx, lx), 0.0f);
    float hh = fmaxf(__fsub_rn(ry, ly), 0.0f);
    float inter = __fmul_rn(ww, hh);
    float den = __fadd_rn(__fsub_rn(__fadd_rn(iar, jar), inter), 1e-7f);
    return __fdiv_rn(inter, den);
}

__device__ __forceinline__ u64 bstep(u64 v, u32 idx, u32 size, u32 stride) {
    u64 v2 = __shfl_xor((unsigned long long)v, (int)stride, 64);
    bool keep_big = (((idx & stride) == 0) == ((idx & size) == 0));
    return ((v > v2) == keep_big) ? v : v2;
}

__device__ __forceinline__ void radix_scan(u32* hist, int nb, int shift, u32* s_scal,
                                           u32* wsum, int tid, int lane, int wid) {
    int per = nb >> 10; if (per == 0) per = 1;
    int na = nb / per;
    u32 rem = s_scal[1];
    u32 Pk = s_scal[0];
    int hi = nb - 1 - per * tid;
    u32 s = 0;
    if (tid < na)
        for (int q = 0; q < per; ++q) s += hist[hi - q];
    u32 pre = s;
#pragma unroll
    for (int off = 1; off < 64; off <<= 1) {
        u32 o = __shfl_up(pre, off);
        if (lane >= off) pre += o;
    }
    if (lane == 63) wsum[wid] = pre;
    __syncthreads();
    u32 base = 0;
    for (int w = 0; w < wid; ++w) base += wsum[w];
    u32 run = base + pre - s;
    if (tid < na) {
        for (int q = 0; q < per; ++q) {
            int d = hi - q;
            u32 g = hist[d];
            if (run < rem && rem <= run + g) {
                s_scal[0] = Pk | ((u32)d << shift);
                s_scal[1] = rem - run;
            }
            run += g;
        }
    }
    __syncthreads();
}

union U2 {
    u32 hist[4096];
    struct { u32 eqw[264]; u32 wpre[264]; } tie;
};

// ---------------- Kernel 2: bin-select (fast) / exact radix (fallback) + sort + NMS + emit ----------------
__global__ __launch_bounds__(1024) void yolo_nms_kernel(const float* __restrict__ preds,
                                                        const u64* __restrict__ keys,
                                                        const float4* __restrict__ obox,
                                                        const u32* __restrict__ hist,
                                                        float* __restrict__ out) {
    const int b = blockIdx.x;
    const int tid = threadIdx.x;
    const int lane = tid & 63;
    const int wid = tid >> 6;   // 0..15

    __shared__ U2 u2;
    __shared__ u64 skey[KBIG];
    __shared__ float BX1[KBIG], BY1[KBIG], BX2[KBIG], BY2[KBIG], BAR[KBIG];
    __shared__ int keptlist[364];
    __shared__ float kx1[364], ky1[364], kx2[364], ky2[364], kar[364];
    __shared__ u32 kcls[364];
    __shared__ u64 rows[64];
    __shared__ u32 wsum[16];
    __shared__ u32 s_scal[4];
    __shared__ u32 s_cnt;
    __shared__ u32 s_csupp[2];
    __shared__ u32 s_nkept;

    const u64* kb = keys + (size_t)b * A_ANCH;

    // score bits in registers
    u32 vals[9];
#pragma unroll
    for (int it = 0; it < 9; ++it) {
        int a = tid + it * 1024;
        vals[it] = (a < A_ANCH) ? (u32)(kb[a] >> 32) : 0u;
    }

    // ---- 256-bin scan of prebuilt hist: bin D of the 512th-largest valid score ----
    const u32* hb = hist + (size_t)b * HBINS;
    {
        u32 g = (tid < HBINS) ? hb[HBINS - 1 - tid] : 0u;   // t=0 -> highest bin
        u32 pre = g;
#pragma unroll
        for (int off = 1; off < 64; off <<= 1) {
            u32 o = __shfl_up(pre, off);
            if (lane >= off) pre += o;
        }
        if (lane == 63) wsum[wid] = pre;
        __syncthreads();
        u32 base = 0;
        for (int w = 0; w < wid; ++w) base += wsum[w];
        pre += base;                      // inclusive count in bins >= (255-tid)
        u32 run = pre - g;                // count strictly above
        if (tid < HBINS) {
            if (run < 512u && 512u <= pre) { s_scal[0] = (u32)(HBINS - 1 - tid); s_scal[2] = pre; }
            if (tid == HBINS - 1) {
                s_scal[3] = pre;                                  // total valid
                if (pre < 512u) { s_scal[0] = 0; s_scal[2] = pre; }   // take all valid
            }
        }
        __syncthreads();
    }
    const u32 Pbin16 = BIN_BASE + s_scal[0];
    const u32 Cfast = s_scal[2];
    const u32 validN = s_scal[3];

    for (int pass = 0; pass < 2; ++pass) {
        u32 Ccand;
        if (pass == 0) {
            if (Cfast > (u32)KBIG) continue;   // degenerate -> exact path
            Ccand = Cfast;
            skey[tid] = 0;
            if (tid == 0) { s_cnt = 0; s_nkept = 0; s_csupp[0] = 0; s_csupp[1] = 0; }
            __syncthreads();
            // compact all candidates with bin >= Pbin16 (order random; sort makes prefix exact)
#pragma unroll
            for (int it = 0; it < 9; ++it) {
                int a = tid + it * 1024;
                u32 v = vals[it];
                bool take = (a < A_ANCH) && (v != 0u) && ((v >> 16) >= Pbin16);
                u64 m = __ballot(take);
                if (m) {
                    int fl = __ffsll((unsigned long long)m) - 1;
                    u32 basep = 0;
                    if (lane == fl) basep = atomicAdd(&s_cnt, (u32)__popcll(m));
                    basep = __shfl(basep, fl);
                    if (take) {
                        u32 pos = basep + (u32)__popcll(m & ((1ull << lane) - 1ull));
                        if (pos < (u32)KBIG) skey[pos] = kb[a];
                    }
                }
            }
            __syncthreads();
        } else {
            // ---- exact top-1024 radix select (fallback; never taken on bench data) ----
            for (int i = tid; i < 4096; i += 1024) u2.hist[i] = 0;
            if (tid == 0) {
                s_scal[0] = 0; s_scal[1] = (u32)KBIG; s_scal[2] = 0;
                s_nkept = 0; s_csupp[0] = 0; s_csupp[1] = 0;
            }
            __syncthreads();
#pragma unroll
            for (int it = 0; it < 9; ++it) {
                int a = tid + it * 1024;
                hadd(u2.hist, vals[it] >> 20, a < A_ANCH, lane);
            }
            __syncthreads();
            radix_scan(u2.hist, 4096, 20, s_scal, wsum, tid, lane, wid);
            for (int i = tid; i < 4096; i += 1024) u2.hist[i] = 0;
            __syncthreads();
            u32 Pk = s_scal[0];
#pragma unroll
            for (int it = 0; it < 9; ++it) {
                int a = tid + it * 1024;
                u32 v = vals[it];
                bool m = (a < A_ANCH) && ((v & 0xFFF00000u) == Pk);
                hadd(u2.hist, (v >> 8) & 4095u, m, lane);
            }
            __syncthreads();
            radix_scan(u2.hist, 4096, 8, s_scal, wsum, tid, lane, wid);
            for (int i = tid; i < 256; i += 1024) u2.hist[i] = 0;
            __syncthreads();
            Pk = s_scal[0];
#pragma unroll
            for (int it = 0; it < 9; ++it) {
                int a = tid + it * 1024;
                u32 v = vals[it];
                bool m = (a < A_ANCH) && ((v & 0xFFFFFF00u) == Pk);
                hadd(u2.hist, v & 255u, m, lane);
            }
            __syncthreads();
            radix_scan(u2.hist, 256, 0, s_scal, wsum, tid, lane, wid);
            const u32 P = s_scal[0];
            const u32 tEq = s_scal[1];
            if (tid < 264) u2.tie.eqw[tid] = 0;
            __syncthreads();
#pragma unroll
            for (int it = 0; it < 9; ++it) {
                int a = tid + it * 1024;
                if (a < A_ANCH && vals[it] == P) atomicOr(&u2.tie.eqw[a >> 5], 1u << (a & 31));
            }
            __syncthreads();
            if (wid == 0) {
                u32 cw[5], loc = 0;
#pragma unroll
                for (int q = 0; q < 5; ++q) {
                    int w2 = lane * 5 + q;
                    u32 e = (w2 < 264) ? u2.tie.eqw[w2] : 0u;
                    cw[q] = (u32)__popc(e); loc += cw[q];
                }
                u32 pre = loc;
#pragma unroll
                for (int off = 1; off < 64; off <<= 1) {
                    u32 o = __shfl_up(pre, off);
                    if (lane >= off) pre += o;
                }
                u32 run = pre - loc;
#pragma unroll
                for (int q = 0; q < 5; ++q) {
                    int w2 = lane * 5 + q;
                    if (w2 < 264) u2.tie.wpre[w2] = run;
                    run += cw[q];
                }
            }
            __syncthreads();
#pragma unroll
            for (int it = 0; it < 9; ++it) {
                int a = tid + it * 1024;
                bool take = false;
                if (a < A_ANCH) {
                    u32 v = vals[it];
                    take = v > P;
                    if (!take && v == P) {
                        u32 r = u2.tie.wpre[a >> 5] +
                                (u32)__popc(u2.tie.eqw[a >> 5] & ((1u << (a & 31)) - 1u));
                        take = (r < tEq);
                    }
                }
                u64 m = __ballot(take);
                if (m) {
                    int fl = __ffsll((unsigned long long)m) - 1;
                    u32 basep = 0;
                    if (lane == fl) basep = atomicAdd(&s_scal[2], (u32)__popcll(m));
                    basep = __shfl(basep, fl);
                    if (take) {
                        u32 pos = basep + (u32)__popcll(m & ((1ull << lane) - 1ull));
                        if (pos < (u32)KBIG) skey[pos] = kb[a];
                    }
                }
            }
            __syncthreads();
            Ccand = KBIG;
        }

        // ---- hybrid bitonic sort of 1024, descending (unique keys -> deterministic) ----
        {
            u64 v = skey[tid];
#pragma unroll
            for (u32 size = 2; size <= 64; size <<= 1)
#pragma unroll
                for (u32 stride = size >> 1; stride >= 1; stride >>= 1)
                    v = bstep(v, (u32)tid, size, stride);
            for (u32 size = 128; size <= 1024; size <<= 1) {
                for (u32 stride = size >> 1; stride >= 64; stride >>= 1) {
                    skey[tid] = v;
                    __syncthreads();
                    u64 v2 = skey[tid ^ stride];
                    bool keep_big = ((((u32)tid & stride) == 0) == (((u32)tid & size) == 0));
                    v = ((v > v2) == keep_big) ? v : v2;
                    __syncthreads();
                }
#pragma unroll
                for (u32 stride = 32; stride >= 1; stride >>= 1)
                    v = bstep(v, (u32)tid, size, stride);
            }
            skey[tid] = v;
            __syncthreads();
        }

        // ---- boxes: one float4 gather from precomputed obox ----
        {
            u64 key = skey[tid];
            int idx = 16383 - (int)((key >> 7) & 16383u);
            if (idx >= A_ANCH || idx < 0) idx = 0;   // zero-pad keys decode OOR; score 0 -> inert
            float4 ob = obox[(size_t)b * A_ANCH + idx];
            BX1[tid] = ob.x; BY1[tid] = ob.y; BX2[tid] = ob.z; BY2[tid] = ob.w;
            BAR[tid] = __fmul_rn(__fsub_rn(ob.z, ob.x), __fsub_rn(ob.w, ob.y));
        }
        __syncthreads();

        // ---- greedy NMS over chunks of 64 ----
        const int nchunks = (int)((Ccand + 63u) >> 6);
        for (int c = 0; c < nchunks; ++c) {
            int j = c * 64 + lane;
            u64 keyj = skey[j];
            float scj = __uint_as_float((u32)(keyj >> 32));
            u32 clsj = (u32)(keyj & 127u);
            float jx1 = BX1[j], jy1 = BY1[j], jx2 = BX2[j], jy2 = BY2[j], jar = BAR[j];

            u32 nk = s_nkept;
            bool suppbit = false;
            for (u32 k = wid; k < nk; k += 16) {
                bool cm = (kcls[k] == clsj);
                if (__ballot(cm)) {      // cross-class IoU exactly 0 (7680 offset)
                    float iou = iou_f(kx1[k], ky1[k], kx2[k], ky2[k], kar[k],
                                      jx1, jy1, jx2, jy2, jar);
                    suppbit |= (cm && (iou > IOU_THR));
                }
            }
            u64 bm = __ballot(suppbit);
            if (bm && lane == 0) {
                atomicOr(&s_csupp[0], (u32)bm);
                atomicOr(&s_csupp[1], (u32)(bm >> 32));
            }
#pragma unroll
            for (int p2 = 0; p2 < 4; ++p2) {
                int i = p2 * 16 + wid;
                int ci = c * 64 + i;
                u32 clsi = (u32)(skey[ci] & 127u);
                u64 m = 0;
                if (__ballot(clsi == clsj)) {
                    float iou = iou_f(BX1[ci], BY1[ci], BX2[ci], BY2[ci], BAR[ci],
                                      jx1, jy1, jx2, jy2, jar);
                    m = __ballot((lane > i) && (iou > IOU_THR));
                }
                if (lane == 0) rows[i] = m;
            }
            __syncthreads();
            if (wid == 0) {
                u64 row = rows[lane];
                u32 rlo = (u32)row, rhi = (u32)(row >> 32);
                u64 csupp = (((u64)s_csupp[1]) << 32) | (u64)s_csupp[0];
                u64 validm = __ballot(scj > CONF_T) & ~csupp;
                u64 supp = 0, keep = 0;
#pragma unroll
                for (int i = 0; i < 64; ++i) {
                    u64 ri = (((u64)(u32)__builtin_amdgcn_readlane((int)rhi, i)) << 32) |
                             (u64)(u32)__builtin_amdgcn_readlane((int)rlo, i);
                    bool ki = (((validm & ~supp) >> i) & 1ull) != 0;
                    if (ki) { keep |= (1ull << i); supp |= ri; }
                }
                u32 basek = s_nkept;
                if ((keep >> lane) & 1ull) {
                    u32 slot = basek + (u32)__popcll(keep & ((1ull << lane) - 1ull));
                    keptlist[slot] = j;
                    kx1[slot] = jx1; ky1[slot] = jy1;
                    kx2[slot] = jx2; ky2[slot] = jy2;
                    kar[slot] = jar; kcls[slot] = clsj;
                }
                if (lane == 0) {
                    s_nkept = basek + (u32)__popcll(keep);
                    s_csupp[0] = 0; s_csupp[1] = 0;
                }
            }
            __syncthreads();
            if (s_nkept >= MAX_DET) break;
        }

        u32 nk = s_nkept;
        bool finished = (nk >= MAX_DET) || (Ccand >= validN) || (pass == 1);
        if (!finished) continue;   // exact fallback (not taken on bench data)

        // ---- emit (plain boxes recomputed from preds: bit-exact) ----
        if (tid < MAX_DET) {
            float row[6];
            int t = (tid < (int)(nk < MAX_DET ? nk : MAX_DET)) ? keptlist[tid] : -1;
            if (t >= 0) {
                u64 key = skey[t];
                float score = __uint_as_float((u32)(key >> 32));
                int cls = (int)(key & 127u);
                int idx = 16383 - (int)((key >> 7) & 16383u);
                const float* pb = preds + (size_t)b * NROWS * A_ANCH + idx;
                float x = pb[0], y = pb[A_ANCH], w = pb[2 * A_ANCH], h = pb[3 * A_ANCH];
                float hw = __fmul_rn(w, 0.5f), hh = __fmul_rn(h, 0.5f);
                row[0] = __fsub_rn(x, hw);
                row[1] = __fsub_rn(y, hh);
                row[2] = __fadd_rn(x, hw);
                row[3] = __fadd_rn(y, hh);
                row[4] = score;
                row[5] = (float)cls;
            } else {
                row[0] = row[1] = row[2] = row[3] = row[4] = row[5] = (float)NC;
            }
            float* o = out + ((size_t)b * MAX_DET + tid) * 6;
#pragma unroll
            for (int q = 0; q < 6; ++q) o[q] = row[q];
        }
        break;
    }
}

extern "C" void kernel_launch(void* const* d_in, const int* in_sizes, int n_in,
                              void* d_out, int out_size, void* d_ws, size_t ws_size,
                              hipStream_t stream) {
    const float* preds = (const float*)d_in[0];
    float* out = (float*)d_out;
    int B = in_sizes[0] / (NROWS * A_ANCH);
    u64* keys = (u64*)d_ws;                                   // B*8400 u64   (2.15 MB @B=32)
    float4* obox = (float4*)(keys + (size_t)B * A_ANCH);      // B*8400 f4    (4.30 MB)
    u32* hist = (u32*)(obox + (size_t)B * A_ANCH);            // B*256 u32    (32 KB)
    (void)hipMemsetAsync(hist, 0, (size_t)B * HBINS * sizeof(u32), stream);
    yolo_conf_kernel<<<dim3(B * 9), dim3(256), 0, stream>>>(preds, keys, obox, hist);
    yolo_nms_kernel<<<dim3(B), dim3(1024), 0, stream>>>(preds, keys, obox, hist, out);
}

// Round 10
// 68.281 us; speedup vs baseline: 1.7915x; 1.1495x over previous
//
#include <hip/hip_runtime.h>
#include <stdint.h>

typedef unsigned long long u64;
typedef unsigned int u32;

#define NC 80
#define CONF_T 0.25f
#define IOU_THR 0.45f
#define MAX_DET 300
#define KBIG 1024
#define A_ANCH 8400
#define NROWS 84
#define MAX_WH 7680.0f
#define HBINS 256
#define BIN_BASE 0x3e80u

// ---------------- Kernel 1 (r3-proven): per-anchor class max/argmax -> packed sort key ----------------
// key = (score_bits << 32) | ((16383 - anchor) << 7) | cls
__global__ __launch_bounds__(512) void yolo_conf_kernel(const float* __restrict__ preds,
                                                        u64* __restrict__ keys) {
    int b = blockIdx.x / 9;
    int g = (blockIdx.x % 9) * 512 + threadIdx.x;    // float2 group
    if (g >= A_ANCH / 2) return;
    int a0 = g * 2;
    const float* base = preds + ((size_t)b * NROWS + 4) * A_ANCH + a0;
    float2 best = *(const float2*)base;
    int bc0 = 0, bc1 = 0;
#pragma unroll 8
    for (int c = 1; c < NC; ++c) {
        float2 v = *(const float2*)(base + (size_t)c * A_ANCH);
        if (v.x > best.x) { best.x = v.x; bc0 = c; }   // strict > = first-max argmax
        if (v.y > best.y) { best.y = v.y; bc1 = c; }
    }
    float s0 = (best.x > CONF_T) ? best.x : 0.0f;
    float s1 = (best.y > CONF_T) ? best.y : 0.0f;
    ulonglong2 kk;
    kk.x = ((u64)__float_as_uint(s0) << 32) | ((u64)(16383 - a0) << 7) | (u64)bc0;
    kk.y = ((u64)__float_as_uint(s1) << 32) | ((u64)(16383 - (a0 + 1)) << 7) | (u64)bc1;
    *(ulonglong2*)(keys + (size_t)b * A_ANCH + a0) = kk;
}

__device__ __forceinline__ float iou_f(float ix1, float iy1, float ix2, float iy2, float iar,
                                       float jx1, float jy1, float jx2, float jy2, float jar) {
    float lx = fmaxf(ix1, jx1), ly = fmaxf(iy1, jy1);
    float rx = fminf(ix2, jx2), ry = fminf(iy2, jy2);
    float ww = fmaxf(__fsub_rn(rx, lx), 0.0f);
    float hh = fmaxf(__fsub_rn(ry, ly), 0.0f);
    float inter = __fmul_rn(ww, hh);
    float den = __fadd_rn(__fsub_rn(__fadd_rn(iar, jar), inter), 1e-7f);
    return __fdiv_rn(inter, den);
}

// adaptive wave histogram add: 1 atomic for the dominant bin, per-lane for stragglers
__device__ __forceinline__ void hadd(u32* h, u32 bin, bool m, int lane) {
    u64 act = __ballot(m);
    if (act == 0) return;
    int fl = __ffsll((unsigned long long)act) - 1;
    u32 fb = __shfl(bin, fl);
    u64 same = __ballot(m && (bin == fb));
    if (lane == fl) atomicAdd(&h[fb], (u32)__popcll(same));
    if (m && (bin != fb)) atomicAdd(&h[bin], 1u);
}

__device__ __forceinline__ u64 bstep(u64 v, u32 idx, u32 size, u32 stride) {
    u64 v2 = __shfl_xor((unsigned long long)v, (int)stride, 64);
    bool keep_big = (((idx & stride) == 0) == ((idx & size) == 0));
    return ((v > v2) == keep_big) ? v : v2;
}

__device__ __forceinline__ void radix_scan(u32* hist, int nb, int shift, u32* s_scal,
                                           u32* wsum, int tid, int lane, int wid) {
    int per = nb >> 10; if (per == 0) per = 1;
    int na = nb / per;
    u32 rem = s_scal[1];
    u32 Pk = s_scal[0];
    int hi = nb - 1 - per * tid;
    u32 s = 0;
    if (tid < na)
        for (int q = 0; q < per; ++q) s += hist[hi - q];
    u32 pre = s;
#pragma unroll
    for (int off = 1; off < 64; off <<= 1) {
        u32 o = __shfl_up(pre, off);
        if (lane >= off) pre += o;
    }
    if (lane == 63) wsum[wid] = pre;
    __syncthreads();
    u32 base = 0;
    for (int w = 0; w < wid; ++w) base += wsum[w];
    u32 run = base + pre - s;
    if (tid < na) {
        for (int q = 0; q < per; ++q) {
            int d = hi - q;
            u32 g = hist[d];
            if (run < rem && rem <= run + g) {
                s_scal[0] = Pk | ((u32)d << shift);
                s_scal[1] = rem - run;
            }
            run += g;
        }
    }
    __syncthreads();
}

union U2 {
    u32 hist[4096];
    struct { u32 eqw[264]; u32 wpre[264]; } tie;
};

// ---------------- Kernel 2: in-kernel 256-bin hist + bin-select (fast) / exact radix (fallback) ----------------
__global__ __launch_bounds__(1024) void yolo_nms_kernel(const float* __restrict__ preds,
                                                        const u64* __restrict__ keys,
                                                        float* __restrict__ out) {
    const int b = blockIdx.x;
    const int tid = threadIdx.x;
    const int lane = tid & 63;
    const int wid = tid >> 6;   // 0..15

    __shared__ U2 u2;
    __shared__ u64 skey[KBIG];
    __shared__ float BX1[KBIG], BY1[KBIG], BX2[KBIG], BY2[KBIG], BAR[KBIG];
    __shared__ int keptlist[364];
    __shared__ float kx1[364], ky1[364], kx2[364], ky2[364], kar[364];
    __shared__ u32 kcls[364];
    __shared__ u64 rows[64];
    __shared__ u32 wsum[16];
    __shared__ u32 s_scal[4];
    __shared__ u32 s_cnt;
    __shared__ u32 s_csupp[2];
    __shared__ u32 s_nkept;

    const u64* kb = keys + (size_t)b * A_ANCH;

    // score bits in registers
    u32 vals[9];
#pragma unroll
    for (int it = 0; it < 9; ++it) {
        int a = tid + it * 1024;
        vals[it] = (a < A_ANCH) ? (u32)(kb[a] >> 32) : 0u;
    }

    // ---- 256-bin LDS histogram of valid scores (bits>>16 - 0x3e80, clamped) ----
    if (tid < HBINS) u2.hist[tid] = 0;
    __syncthreads();
#pragma unroll
    for (int it = 0; it < 9; ++it) {
        int a = tid + it * 1024;
        u32 v = vals[it];
        u32 bin = (v >> 16) - BIN_BASE;
        if (bin > 255u) bin = 255u;
        hadd(u2.hist, bin, (a < A_ANCH) && (v != 0u), lane);
    }
    __syncthreads();

    // ---- scan: bin D of the 512th-largest valid score; validN = total ----
    {
        u32 g = (tid < HBINS) ? u2.hist[HBINS - 1 - tid] : 0u;   // t=0 -> highest bin
        u32 pre = g;
#pragma unroll
        for (int off = 1; off < 64; off <<= 1) {
            u32 o = __shfl_up(pre, off);
            if (lane >= off) pre += o;
        }
        if (lane == 63) wsum[wid] = pre;
        __syncthreads();
        u32 base = 0;
        for (int w = 0; w < wid; ++w) base += wsum[w];
        pre += base;                      // inclusive count in bins >= (255-tid)
        u32 run = pre - g;                // count strictly above
        if (tid < HBINS) {
            if (run < 512u && 512u <= pre) { s_scal[0] = (u32)(HBINS - 1 - tid); s_scal[2] = pre; }
            if (tid == HBINS - 1) {
                s_scal[3] = pre;                                  // total valid
                if (pre < 512u) { s_scal[0] = 0; s_scal[2] = pre; }   // take all valid
            }
        }
        __syncthreads();
    }
    const u32 Pbin16 = BIN_BASE + s_scal[0];
    const u32 Cfast = s_scal[2];
    const u32 validN = s_scal[3];

    for (int pass = 0; pass < 2; ++pass) {
        u32 Ccand;
        if (pass == 0) {
            if (Cfast > (u32)KBIG) continue;   // degenerate -> exact path
            Ccand = Cfast;
            skey[tid] = 0;
            if (tid == 0) { s_cnt = 0; s_nkept = 0; s_csupp[0] = 0; s_csupp[1] = 0; }
            __syncthreads();
            // compact all candidates with bin >= Pbin16 (order random; sort makes prefix exact)
#pragma unroll
            for (int it = 0; it < 9; ++it) {
                int a = tid + it * 1024;
                u32 v = vals[it];
                bool take = (a < A_ANCH) && (v != 0u) && ((v >> 16) >= Pbin16);
                u64 m = __ballot(take);
                if (m) {
                    int fl = __ffsll((unsigned long long)m) - 1;
                    u32 basep = 0;
                    if (lane == fl) basep = atomicAdd(&s_cnt, (u32)__popcll(m));
                    basep = __shfl(basep, fl);
                    if (take) {
                        u32 pos = basep + (u32)__popcll(m & ((1ull << lane) - 1ull));
                        if (pos < (u32)KBIG) skey[pos] = kb[a];
                    }
                }
            }
            __syncthreads();
        } else {
            // ---- exact top-1024 radix select (fallback; never taken on bench data) ----
            for (int i = tid; i < 4096; i += 1024) u2.hist[i] = 0;
            if (tid == 0) {
                s_scal[0] = 0; s_scal[1] = (u32)KBIG; s_scal[2] = 0;
                s_nkept = 0; s_csupp[0] = 0; s_csupp[1] = 0;
            }
            __syncthreads();
#pragma unroll
            for (int it = 0; it < 9; ++it) {
                int a = tid + it * 1024;
                hadd(u2.hist, vals[it] >> 20, a < A_ANCH, lane);
            }
            __syncthreads();
            radix_scan(u2.hist, 4096, 20, s_scal, wsum, tid, lane, wid);
            for (int i = tid; i < 4096; i += 1024) u2.hist[i] = 0;
            __syncthreads();
            u32 Pk = s_scal[0];
#pragma unroll
            for (int it = 0; it < 9; ++it) {
                int a = tid + it * 1024;
                u32 v = vals[it];
                bool m = (a < A_ANCH) && ((v & 0xFFF00000u) == Pk);
                hadd(u2.hist, (v >> 8) & 4095u, m, lane);
            }
            __syncthreads();
            radix_scan(u2.hist, 4096, 8, s_scal, wsum, tid, lane, wid);
            for (int i = tid; i < 256; i += 1024) u2.hist[i] = 0;
            __syncthreads();
            Pk = s_scal[0];
#pragma unroll
            for (int it = 0; it < 9; ++it) {
                int a = tid + it * 1024;
                u32 v = vals[it];
                bool m = (a < A_ANCH) && ((v & 0xFFFFFF00u) == Pk);
                hadd(u2.hist, v & 255u, m, lane);
            }
            __syncthreads();
            radix_scan(u2.hist, 256, 0, s_scal, wsum, tid, lane, wid);
            const u32 P = s_scal[0];
            const u32 tEq = s_scal[1];
            if (tid < 264) u2.tie.eqw[tid] = 0;
            __syncthreads();
#pragma unroll
            for (int it = 0; it < 9; ++it) {
                int a = tid + it * 1024;
                if (a < A_ANCH && vals[it] == P) atomicOr(&u2.tie.eqw[a >> 5], 1u << (a & 31));
            }
            __syncthreads();
            if (wid == 0) {
                u32 cw[5], loc = 0;
#pragma unroll
                for (int q = 0; q < 5; ++q) {
                    int w2 = lane * 5 + q;
                    u32 e = (w2 < 264) ? u2.tie.eqw[w2] : 0u;
                    cw[q] = (u32)__popc(e); loc += cw[q];
                }
                u32 pre = loc;
#pragma unroll
                for (int off = 1; off < 64; off <<= 1) {
                    u32 o = __shfl_up(pre, off);
                    if (lane >= off) pre += o;
                }
                u32 run = pre - loc;
#pragma unroll
                for (int q = 0; q < 5; ++q) {
                    int w2 = lane * 5 + q;
                    if (w2 < 264) u2.tie.wpre[w2] = run;
                    run += cw[q];
                }
            }
            __syncthreads();
#pragma unroll
            for (int it = 0; it < 9; ++it) {
                int a = tid + it * 1024;
                bool take = false;
                if (a < A_ANCH) {
                    u32 v = vals[it];
                    take = v > P;
                    if (!take && v == P) {
                        u32 r = u2.tie.wpre[a >> 5] +
                                (u32)__popc(u2.tie.eqw[a >> 5] & ((1u << (a & 31)) - 1u));
                        take = (r < tEq);
                    }
                }
                u64 m = __ballot(take);
                if (m) {
                    int fl = __ffsll((unsigned long long)m) - 1;
                    u32 basep = 0;
                    if (lane == fl) basep = atomicAdd(&s_scal[2], (u32)__popcll(m));
                    basep = __shfl(basep, fl);
                    if (take) {
                        u32 pos = basep + (u32)__popcll(m & ((1ull << lane) - 1ull));
                        if (pos < (u32)KBIG) skey[pos] = kb[a];
                    }
                }
            }
            __syncthreads();
            Ccand = KBIG;
        }

        // ---- hybrid bitonic sort of 1024, descending (unique keys -> deterministic) ----
        {
            u64 v = skey[tid];
#pragma unroll
            for (u32 size = 2; size <= 64; size <<= 1)
#pragma unroll
                for (u32 stride = size >> 1; stride >= 1; stride >>= 1)
                    v = bstep(v, (u32)tid, size, stride);
            for (u32 size = 128; size <= 1024; size <<= 1) {
                for (u32 stride = size >> 1; stride >= 64; stride >>= 1) {
                    skey[tid] = v;
                    __syncthreads();
                    u64 v2 = skey[tid ^ stride];
                    bool keep_big = ((((u32)tid & stride) == 0) == (((u32)tid & size) == 0));
                    v = ((v > v2) == keep_big) ? v : v2;
                    __syncthreads();
                }
#pragma unroll
                for (u32 stride = 32; stride >= 1; stride >>= 1)
                    v = bstep(v, (u32)tid, size, stride);
            }
            skey[tid] = v;
            __syncthreads();
        }

        // ---- offset boxes from preds (bit-exact chain; r7-proven) ----
        {
            u64 key = skey[tid];
            int cls = (int)(key & 127u);
            int idx = 16383 - (int)((key >> 7) & 16383u);
            if (idx >= A_ANCH || idx < 0) idx = 0;   // zero-pad keys decode OOR; score 0 -> inert
            const float* pb = preds + (size_t)b * NROWS * A_ANCH + idx;
            float x = pb[0];
            float y = pb[A_ANCH];
            float w = pb[2 * A_ANCH];
            float h = pb[3 * A_ANCH];
            float hw = __fmul_rn(w, 0.5f), hh = __fmul_rn(h, 0.5f);
            float x1 = __fsub_rn(x, hw), x2 = __fadd_rn(x, hw);
            float y1 = __fsub_rn(y, hh), y2 = __fadd_rn(y, hh);
            float off = __fmul_rn((float)cls, MAX_WH);
            float bx1 = __fadd_rn(x1, off), bx2 = __fadd_rn(x2, off);
            float by1 = __fadd_rn(y1, off), by2 = __fadd_rn(y2, off);
            BX1[tid] = bx1; BY1[tid] = by1; BX2[tid] = bx2; BY2[tid] = by2;
            BAR[tid] = __fmul_rn(__fsub_rn(bx2, bx1), __fsub_rn(by2, by1)); // area of OFFSET box
        }
        __syncthreads();

        // ---- greedy NMS over chunks of 64 ----
        const int nchunks = (int)((Ccand + 63u) >> 6);
        for (int c = 0; c < nchunks; ++c) {
            int j = c * 64 + lane;
            u64 keyj = skey[j];
            float scj = __uint_as_float((u32)(keyj >> 32));
            u32 clsj = (u32)(keyj & 127u);
            float jx1 = BX1[j], jy1 = BY1[j], jx2 = BX2[j], jy2 = BY2[j], jar = BAR[j];

            u32 nk = s_nkept;
            bool suppbit = false;
            for (u32 k = wid; k < nk; k += 16) {
                bool cm = (kcls[k] == clsj);
                if (__ballot(cm)) {      // cross-class IoU exactly 0 (7680 offset)
                    float iou = iou_f(kx1[k], ky1[k], kx2[k], ky2[k], kar[k],
                                      jx1, jy1, jx2, jy2, jar);
                    suppbit |= (cm && (iou > IOU_THR));
                }
            }
            u64 bm = __ballot(suppbit);
            if (bm && lane == 0) {
                atomicOr(&s_csupp[0], (u32)bm);
                atomicOr(&s_csupp[1], (u32)(bm >> 32));
            }
#pragma unroll
            for (int p2 = 0; p2 < 4; ++p2) {
                int i = p2 * 16 + wid;
                int ci = c * 64 + i;
                u32 clsi = (u32)(skey[ci] & 127u);
                u64 m = 0;
                if (__ballot(clsi == clsj)) {
                    float iou = iou_f(BX1[ci], BY1[ci], BX2[ci], BY2[ci], BAR[ci],
                                      jx1, jy1, jx2, jy2, jar);
                    m = __ballot((lane > i) && (iou > IOU_THR));
                }
                if (lane == 0) rows[i] = m;
            }
            __syncthreads();
            if (wid == 0) {
                u64 row = rows[lane];
                u32 rlo = (u32)row, rhi = (u32)(row >> 32);
                u64 csupp = (((u64)s_csupp[1]) << 32) | (u64)s_csupp[0];
                u64 validm = __ballot(scj > CONF_T) & ~csupp;
                u64 supp = 0, keep = 0;
#pragma unroll
                for (int i = 0; i < 64; ++i) {
                    u64 ri = (((u64)(u32)__builtin_amdgcn_readlane((int)rhi, i)) << 32) |
                             (u64)(u32)__builtin_amdgcn_readlane((int)rlo, i);
                    bool ki = (((validm & ~supp) >> i) & 1ull) != 0;
                    if (ki) { keep |= (1ull << i); supp |= ri; }
                }
                u32 basek = s_nkept;
                if ((keep >> lane) & 1ull) {
                    u32 slot = basek + (u32)__popcll(keep & ((1ull << lane) - 1ull));
                    keptlist[slot] = j;
                    kx1[slot] = jx1; ky1[slot] = jy1;
                    kx2[slot] = jx2; ky2[slot] = jy2;
                    kar[slot] = jar; kcls[slot] = clsj;
                }
                if (lane == 0) {
                    s_nkept = basek + (u32)__popcll(keep);
                    s_csupp[0] = 0; s_csupp[1] = 0;
                }
            }
            __syncthreads();
            if (s_nkept >= MAX_DET) break;
        }

        u32 nk = s_nkept;
        bool finished = (nk >= MAX_DET) || (Ccand >= validN) || (pass == 1);
        if (!finished) continue;   // exact fallback (not taken on bench data)

        // ---- emit (plain boxes recomputed from preds: bit-exact) ----
        if (tid < MAX_DET) {
            float row[6];
            int t = (tid < (int)(nk < MAX_DET ? nk : MAX_DET)) ? keptlist[tid] : -1;
            if (t >= 0) {
                u64 key = skey[t];
                float score = __uint_as_float((u32)(key >> 32));
                int cls = (int)(key & 127u);
                int idx = 16383 - (int)((key >> 7) & 16383u);
                const float* pb = preds + (size_t)b * NROWS * A_ANCH + idx;
                float x = pb[0], y = pb[A_ANCH], w = pb[2 * A_ANCH], h = pb[3 * A_ANCH];
                float hw = __fmul_rn(w, 0.5f), hh = __fmul_rn(h, 0.5f);
                row[0] = __fsub_rn(x, hw);
                row[1] = __fsub_rn(y, hh);
                row[2] = __fadd_rn(x, hw);
                row[3] = __fadd_rn(y, hh);
                row[4] = score;
                row[5] = (float)cls;
            } else {
                row[0] = row[1] = row[2] = row[3] = row[4] = row[5] = (float)NC;
            }
            float* o = out + ((size_t)b * MAX_DET + tid) * 6;
#pragma unroll
            for (int q = 0; q < 6; ++q) o[q] = row[q];
        }
        break;
    }
}

extern "C" void kernel_launch(void* const* d_in, const int* in_sizes, int n_in,
                              void* d_out, int out_size, void* d_ws, size_t ws_size,
                              hipStream_t stream) {
    const float* preds = (const float*)d_in[0];
    float* out = (float*)d_out;
    u64* keys = (u64*)d_ws;   // B * 8400 u64 ~= 2.1 MB
    int B = in_sizes[0] / (NROWS * A_ANCH);
    yolo_conf_kernel<<<dim3(B * 9), dim3(512), 0, stream>>>(preds, keys);
    yolo_nms_kernel<<<dim3(B), dim3(1024), 0, stream>>>(preds, keys, out);
}